// Round 8
// baseline (347.858 us; speedup 1.0000x reference)
//
#include <hip/hip_runtime.h>
#include <stdint.h>

typedef unsigned short u16;
typedef short s16x8 __attribute__((ext_vector_type(8)));
typedef float f32x4 __attribute__((ext_vector_type(4)));

#define BM 128
#define BN 128
#define BK 32
#define KPAD 40   // padded LDS row stride for the legacy (non-async) kernel

__device__ __forceinline__ float bf2f(u16 b) {
    union { unsigned int u; float f; } v; v.u = ((unsigned int)b) << 16; return v.f;
}
__device__ __forceinline__ u16 f2bf(float f) {
    union { float f; unsigned int u; } v; v.f = f;
    unsigned int u = v.u;
    u += 0x7fffu + ((u >> 16) & 1u);   // RNE
    return (u16)(u >> 16);
}
__device__ __forceinline__ void async_cp16(const u16* g, u16* l) {
    // global -> LDS direct copy, 16 B per lane; LDS dest = wave-uniform base + lane*16
    __builtin_amdgcn_global_load_lds((const __attribute__((address_space(1))) void*)g,
                                     (__attribute__((address_space(3))) void*)l, 16, 0, 0);
}

// ---------------- GroupNorm statistics: one block per (b,g), fp32 input ----------------
__global__ __launch_bounds__(256) void gn_stats(const float* __restrict__ x,
                                                float* __restrict__ mean,
                                                float* __restrict__ rstd) {
    const int bg = blockIdx.x;
    const float* p = x + (long)bg * 16 * 2048;     // 32768 fp32 per group
    float s = 0.f, ss = 0.f;
    for (int it = 0; it < 32; it++) {
        const float4 v = *reinterpret_cast<const float4*>(p + ((it * 256 + threadIdx.x) << 2));
        s += v.x + v.y + v.z + v.w;
        ss += v.x * v.x + v.y * v.y + v.z * v.z + v.w * v.w;
    }
    const int lane = threadIdx.x & 63, wave = threadIdx.x >> 6;
#pragma unroll
    for (int o = 32; o > 0; o >>= 1) { s += __shfl_down(s, o, 64); ss += __shfl_down(ss, o, 64); }
    __shared__ float rb[8];
    if (lane == 0) { rb[wave] = s; rb[4 + wave] = ss; }
    __syncthreads();
    if (threadIdx.x == 0) {
        float S = rb[0] + rb[1] + rb[2] + rb[3];
        float SS = rb[4] + rb[5] + rb[6] + rb[7];
        float mu = S * (1.f / 32768.f);
        float var = SS * (1.f / 32768.f) - mu * mu;
        mean[bg] = mu;
        rstd[bg] = rsqrtf(var + 1e-6f);
    }
}

// ---------- GroupNorm apply + transpose: fp32 x -> bf16 hnT[h, c] ----------
__global__ __launch_bounds__(256) void gn_apply_t(const float* __restrict__ x,
                                                  const float* __restrict__ gamma,
                                                  const float* __restrict__ beta,
                                                  const float* __restrict__ mean,
                                                  const float* __restrict__ rstd,
                                                  u16* __restrict__ hnT) {
    const int b = blockIdx.z, c0 = blockIdx.y * 64, h0 = blockIdx.x * 64;
    __shared__ __align__(16) u16 T[64][72];
    const int tid = threadIdx.x;
#pragma unroll
    for (int sidx = 0; sidx < 4; sidx++) {
        int ch = tid + sidx * 256;                 // 1024 float4-chunks
        int cc = ch >> 4, h4 = (ch & 15) * 4;
        int c = c0 + cc;
        float mu = mean[b * 32 + (c >> 4)], rs = rstd[b * 32 + (c >> 4)];
        float ga = gamma[c], be = beta[c];
        const float4 v = *reinterpret_cast<const float4*>(x + ((long)b * 512 + c) * 2048 + h0 + h4);
        ushort4 pk;
        pk.x = f2bf((v.x - mu) * rs * ga + be);
        pk.y = f2bf((v.y - mu) * rs * ga + be);
        pk.z = f2bf((v.z - mu) * rs * ga + be);
        pk.w = f2bf((v.w - mu) * rs * ga + be);
        *reinterpret_cast<ushort4*>(&T[cc][h4]) = pk;
    }
    __syncthreads();
#pragma unroll
    for (int sidx = 0; sidx < 2; sidx++) {
        int ch = tid + sidx * 256;                 // 512 uint4-chunks
        int hh = ch >> 3, c8 = (ch & 7) * 8;
        unsigned int o[4];
#pragma unroll
        for (int i = 0; i < 4; i++) {
            u16 lo = T[c8 + 2 * i][hh];
            u16 hi = T[c8 + 2 * i + 1][hh];
            o[i] = (unsigned int)lo | ((unsigned int)hi << 16);
        }
        *reinterpret_cast<uint4*>(hnT + ((long)b * 2048 + h0 + hh) * 512 + c0 + c8) =
            uint4{o[0], o[1], o[2], o[3]};
    }
}

// ---------------- fp32 -> bf16 weight conversion (512x512 each, y selects src) ----------------
__global__ __launch_bounds__(256) void w2bf(const float* __restrict__ a,
                                            const float* __restrict__ b,
                                            const float* __restrict__ c,
                                            u16* __restrict__ dst) {
    const float* s = (blockIdx.y == 0) ? a : (blockIdx.y == 1) ? b : c;
    const int i = (blockIdx.x * 256 + threadIdx.x) * 4;
    const float4 v = *reinterpret_cast<const float4*>(s + i);
    ushort4 p;
    p.x = f2bf(v.x); p.y = f2bf(v.y); p.z = f2bf(v.z); p.w = f2bf(v.w);
    *reinterpret_cast<ushort4*>(dst + (long)blockIdx.y * 262144 + i) = p;
}

// ------------------ softmax over rows of S[i, :] (bf16) in place (fallback tiers) ------------------
__global__ __launch_bounds__(256) void softmax_rows(u16* __restrict__ S) {
    u16* p = S + (long)blockIdx.x * 2048;
    const int tid = threadIdx.x;
    uint4 v = *reinterpret_cast<const uint4*>(p + (tid << 3));
    unsigned int w[4] = {v.x, v.y, v.z, v.w};
    float f[8];
#pragma unroll
    for (int i = 0; i < 4; i++) {
        f[2 * i]     = bf2f((u16)(w[i] & 0xffffu));
        f[2 * i + 1] = bf2f((u16)(w[i] >> 16));
    }
    float m = f[0];
#pragma unroll
    for (int i = 1; i < 8; i++) m = fmaxf(m, f[i]);
    const int lane = tid & 63, wave = tid >> 6;
#pragma unroll
    for (int o = 32; o > 0; o >>= 1) m = fmaxf(m, __shfl_down(m, o, 64));
    __shared__ float rb[4];
    __shared__ float bc;
    if (lane == 0) rb[wave] = m;
    __syncthreads();
    if (tid == 0) bc = fmaxf(fmaxf(rb[0], rb[1]), fmaxf(rb[2], rb[3]));
    __syncthreads();
    m = bc;
    float s = 0.f;
#pragma unroll
    for (int i = 0; i < 8; i++) { f[i] = __expf(f[i] - m); s += f[i]; }
#pragma unroll
    for (int o = 32; o > 0; o >>= 1) s += __shfl_down(s, o, 64);
    __syncthreads();
    if (lane == 0) rb[wave] = s;
    __syncthreads();
    if (tid == 0) bc = 1.f / (rb[0] + rb[1] + rb[2] + rb[3]);
    __syncthreads();
    const float inv = bc;
#pragma unroll
    for (int i = 0; i < 4; i++)
        w[i] = (unsigned int)f2bf(f[2 * i] * inv) | ((unsigned int)f2bf(f[2 * i + 1] * inv) << 16);
    *reinterpret_cast<uint4*>(p + (tid << 3)) = uint4{w[0], w[1], w[2], w[3]};
}

// -------- per-row softmax stats: one wave per row of S[16384][2048] --------
__global__ __launch_bounds__(256) void row_stats(const u16* __restrict__ S,
                                                 float* __restrict__ mrow,
                                                 float* __restrict__ linv) {
    const int r = blockIdx.x * 4 + (threadIdx.x >> 6);
    const int lane = threadIdx.x & 63;
    const u16* p = S + (long)r * 2048;
    float f[32];
#pragma unroll
    for (int seg = 0; seg < 4; seg++) {
        const uint4 v = *reinterpret_cast<const uint4*>(p + seg * 512 + lane * 8);
        const unsigned int w[4] = {v.x, v.y, v.z, v.w};
#pragma unroll
        for (int i = 0; i < 4; i++) {
            f[seg * 8 + 2 * i]     = bf2f((u16)(w[i] & 0xffffu));
            f[seg * 8 + 2 * i + 1] = bf2f((u16)(w[i] >> 16));
        }
    }
    float m = f[0];
#pragma unroll
    for (int i = 1; i < 32; i++) m = fmaxf(m, f[i]);
#pragma unroll
    for (int o = 32; o > 0; o >>= 1) m = fmaxf(m, __shfl_down(m, o, 64));
    m = __shfl(m, 0, 64);
    float s = 0.f;
#pragma unroll
    for (int i = 0; i < 32; i++) s += __expf(f[i] - m);
#pragma unroll
    for (int o = 32; o > 0; o >>= 1) s += __shfl_down(s, o, 64);
    if (lane == 0) { mrow[r] = m; linv[r] = 1.f / s; }
}

// ======== fused softmax+PV GEMM: hT[i,c] = sum_j softmax(S)[i,j] * vv[c,j] ========
// 64x128 tile, 1024 blocks (4 blocks/CU); A staged via VGPR with exp applied,
// B staged async; manual software pipeline (A-load issued one phase early).
__global__ __launch_bounds__(256) void pv_fused(const u16* __restrict__ S,
                                                const u16* __restrict__ vv,
                                                const float* __restrict__ mrow,
                                                const float* __restrict__ linv,
                                                u16* __restrict__ hT) {
    const long HH = 4194304, HC = 1048576;
    const int b = blockIdx.z;
    const u16* A = S + (long)b * HH;        // [2048][2048]
    const u16* B = vv + (long)b * HC;       // [512][2048]
    u16* O = hT + (long)b * HC;             // [2048][512]
    const int m0 = blockIdx.y * 64;
    const int n0 = blockIdx.x * 128;

    __shared__ __align__(16) u16 As[2][64 * 32];    // 2 x 4 KB
    __shared__ __align__(16) u16 Bs[2][128 * 32];   // 2 x 8 KB
    __shared__ float ms[64], ls[64];

    const int tid = threadIdx.x;
    const int wave = tid >> 6;
    const int lane = tid & 63;
    const int quad = lane >> 4;
    const int l16 = lane & 15;
    const int wm = (wave >> 1) * 32;
    const int wn = (wave & 1) * 64;
    const int rl = lane >> 2;
    const int cl = (lane & 3) * 8;
    const int ar = tid >> 2;                // A staging row 0..63
    const int ac = (tid & 3) * 8;           // A staging col {0,8,16,24}

    if (tid < 64) {
        ms[tid] = mrow[b * 2048 + m0 + tid];
        ls[tid] = linv[b * 2048 + m0 + tid];
    }

    f32x4 acc[2][4];
#pragma unroll
    for (int i = 0; i < 2; i++)
#pragma unroll
        for (int j = 0; j < 4; j++) acc[i][j] = f32x4{0.f, 0.f, 0.f, 0.f};

    auto load_a = [&](int k0) -> uint4 {
        return *reinterpret_cast<const uint4*>(A + (long)(m0 + ar) * 2048 + k0 + ac);
    };
    auto finish_a = [&](int buf, uint4 v) {
        const float mm = ms[ar];
        const float li = ls[ar];
        const unsigned int w[4] = {v.x, v.y, v.z, v.w};
        unsigned int o[4];
#pragma unroll
        for (int i = 0; i < 4; i++) {
            float a = __expf(bf2f((u16)(w[i] & 0xffffu)) - mm) * li;
            float d = __expf(bf2f((u16)(w[i] >> 16)) - mm) * li;
            o[i] = (unsigned int)f2bf(a) | ((unsigned int)f2bf(d) << 16);
        }
        *reinterpret_cast<uint4*>(&As[buf][ar * 32 + ac]) = uint4{o[0], o[1], o[2], o[3]};
    };
    auto stage_b = [&](int buf, int k0) {
#pragma unroll
        for (int j = 0; j < 2; j++) {
            const int rbase = wave * 32 + j * 16;
            async_cp16(B + (long)(n0 + rbase + rl) * 2048 + k0 + cl, &Bs[buf][rbase * 32]);
        }
    };
    auto compute = [&](int buf) {
        s16x8 af[2], bf4[4];
#pragma unroll
        for (int i = 0; i < 2; i++)
            af[i] = *reinterpret_cast<const s16x8*>(&As[buf][(wm + i * 16 + l16) * 32 + quad * 8]);
#pragma unroll
        for (int j = 0; j < 4; j++)
            bf4[j] = *reinterpret_cast<const s16x8*>(&Bs[buf][(wn + j * 16 + l16) * 32 + quad * 8]);
#pragma unroll
        for (int i = 0; i < 2; i++)
#pragma unroll
            for (int j = 0; j < 4; j++)
                acc[i][j] = __builtin_amdgcn_mfma_f32_16x16x32_bf16(af[i], bf4[j], acc[i][j], 0, 0, 0);
    };

    // prologue: buf0
    uint4 av = load_a(0);
    stage_b(0, 0);
    __syncthreads();                        // ms/ls visible
    finish_a(0, av);

    for (int k0 = 0; k0 < 2048; k0 += 64) {
        uint4 av1 = load_a(k0 + 32);        // issue early: latency hidden past barrier
        __syncthreads();                    // buf0 complete (A ds_writes + B async)
        stage_b(1, k0 + 32);
        compute(0);
        finish_a(1, av1);
        __syncthreads();                    // buf1 complete
        if (k0 + 64 < 2048) { av = load_a(k0 + 64); stage_b(0, k0 + 64); }
        compute(1);
        if (k0 + 64 < 2048) finish_a(0, av);
    }

#pragma unroll
    for (int i = 0; i < 2; i++) {
        const int mb = m0 + wm + i * 16 + quad * 4;
#pragma unroll
        for (int j = 0; j < 4; j++) {
            const int n = n0 + wn + j * 16 + l16;
#pragma unroll
            for (int r = 0; r < 4; r++)
                O[(long)(mb + r) * 512 + n] = f2bf(acc[i][j][r]);
        }
    }
}

// ===================== ASYNC double-buffered MFMA GEMM (bf16 operands) =====================
template <int EPI>
__global__ __launch_bounds__(256) void gemm_tn_a(const u16* __restrict__ Ag, long sA,
                                                 const u16* __restrict__ Bg, long sB,
                                                 const float* __restrict__ bias,
                                                 const float* __restrict__ Xg, long sX,
                                                 void* __restrict__ Ogv, long sO,
                                                 int K, int lda, int ldb, int ldo,
                                                 float scale) {
    const int b = blockIdx.z;
    Ag += (long)b * sA;
    Bg += (long)b * sB;
    const int m0 = blockIdx.y * BM;
    const int n0 = blockIdx.x * BN;

    __shared__ __align__(16) u16 As[2][BM * BK];
    __shared__ __align__(16) u16 Bs[2][BN * BK];

    const int tid = threadIdx.x;
    const int wave = tid >> 6;
    const int lane = tid & 63;
    const int quad = lane >> 4;
    const int l16 = lane & 15;
    const int wm = (wave >> 1) * 64;
    const int wn = (wave & 1) * 64;
    const int rl = lane >> 2;
    const int cl = (lane & 3) * 8;

    f32x4 acc[4][4];
#pragma unroll
    for (int i = 0; i < 4; i++)
#pragma unroll
        for (int j = 0; j < 4; j++) acc[i][j] = f32x4{0.f, 0.f, 0.f, 0.f};

    auto stage = [&](int buf, int k0) {
#pragma unroll
        for (int j = 0; j < 2; j++) {
            const int rbase = wave * 32 + j * 16;
            async_cp16(Ag + (long)(m0 + rbase + rl) * lda + k0 + cl, &As[buf][rbase * BK]);
            async_cp16(Bg + (long)(n0 + rbase + rl) * ldb + k0 + cl, &Bs[buf][rbase * BK]);
        }
    };
    auto compute = [&](int buf) {
        s16x8 af[4], bfr[4];
#pragma unroll
        for (int i = 0; i < 4; i++)
            af[i] = *reinterpret_cast<const s16x8*>(&As[buf][(wm + i * 16 + l16) * BK + quad * 8]);
#pragma unroll
        for (int j = 0; j < 4; j++)
            bfr[j] = *reinterpret_cast<const s16x8*>(&Bs[buf][(wn + j * 16 + l16) * BK + quad * 8]);
#pragma unroll
        for (int i = 0; i < 4; i++)
#pragma unroll
            for (int j = 0; j < 4; j++)
                acc[i][j] = __builtin_amdgcn_mfma_f32_16x16x32_bf16(af[i], bfr[j], acc[i][j], 0, 0, 0);
    };

    stage(0, 0);
    for (int k0 = 0; k0 < K; k0 += 2 * BK) {
        __syncthreads();
        stage(1, k0 + BK);
        compute(0);
        __syncthreads();
        if (k0 + 2 * BK < K) stage(0, k0 + 2 * BK);
        compute(1);
    }

#pragma unroll
    for (int i = 0; i < 4; i++) {
        const int mb = m0 + wm + i * 16 + quad * 4;
#pragma unroll
        for (int j = 0; j < 4; j++) {
            const int n = n0 + wn + j * 16 + l16;
            if (EPI == 0) {
                u16* O = (u16*)Ogv + (long)b * sO;
#pragma unroll
                for (int r = 0; r < 4; r++) {
                    float vv = acc[i][j][r] * scale;
                    if (bias) vv += bias[mb + r];
                    O[(long)(mb + r) * ldo + n] = f2bf(vv);
                }
            } else if (EPI == 1) {
                u16* O = (u16*)Ogv + (long)b * sO;
                ushort4 pk;
                pk.x = f2bf(acc[i][j][0] + bias[mb + 0]);
                pk.y = f2bf(acc[i][j][1] + bias[mb + 1]);
                pk.z = f2bf(acc[i][j][2] + bias[mb + 2]);
                pk.w = f2bf(acc[i][j][3] + bias[mb + 3]);
                *reinterpret_cast<ushort4*>(&O[(long)n * ldo + mb]) = pk;
            } else {
                float* O = (float*)Ogv + (long)b * sO;
                const float* X = Xg + (long)b * sX;
                const float bn = bias[n];
                const float4 xv = *reinterpret_cast<const float4*>(&X[(long)n * ldo + mb]);
                float4 pk;
                pk.x = acc[i][j][0] + bn + xv.x;
                pk.y = acc[i][j][1] + bn + xv.y;
                pk.z = acc[i][j][2] + bn + xv.z;
                pk.w = acc[i][j][3] + bn + xv.w;
                *reinterpret_cast<float4*>(&O[(long)n * ldo + mb]) = pk;
            }
        }
    }
}

// ===================== merged QKV GEMM (z = batch*3 + which), dbuf async =====================
__global__ __launch_bounds__(256) void qkv_a(const u16* __restrict__ wb3,
                                             const u16* __restrict__ hnT,
                                             const float* __restrict__ bq,
                                             const float* __restrict__ bk,
                                             const float* __restrict__ bv,
                                             u16* __restrict__ qT, u16* __restrict__ kT,
                                             u16* __restrict__ vv) {
    const long HC = 1048576;
    const int z = blockIdx.z;
    const int which = z % 3, b = z / 3;
    const u16* Ag = wb3 + which * 262144;
    const u16* Bg = hnT + (long)b * HC;
    const int m0 = blockIdx.y * BM;
    const int n0 = blockIdx.x * BN;

    __shared__ __align__(16) u16 As[2][BM * BK];
    __shared__ __align__(16) u16 Bs[2][BN * BK];

    const int tid = threadIdx.x;
    const int wave = tid >> 6;
    const int lane = tid & 63;
    const int quad = lane >> 4;
    const int l16 = lane & 15;
    const int wm = (wave >> 1) * 64;
    const int wn = (wave & 1) * 64;
    const int rl = lane >> 2;
    const int cl = (lane & 3) * 8;

    f32x4 acc[4][4];
#pragma unroll
    for (int i = 0; i < 4; i++)
#pragma unroll
        for (int j = 0; j < 4; j++) acc[i][j] = f32x4{0.f, 0.f, 0.f, 0.f};

    auto stage = [&](int buf, int k0) {
#pragma unroll
        for (int j = 0; j < 2; j++) {
            const int rbase = wave * 32 + j * 16;
            async_cp16(Ag + (long)(m0 + rbase + rl) * 512 + k0 + cl, &As[buf][rbase * BK]);
            async_cp16(Bg + (long)(n0 + rbase + rl) * 512 + k0 + cl, &Bs[buf][rbase * BK]);
        }
    };
    auto compute = [&](int buf) {
        s16x8 af[4], bfr[4];
#pragma unroll
        for (int i = 0; i < 4; i++)
            af[i] = *reinterpret_cast<const s16x8*>(&As[buf][(wm + i * 16 + l16) * BK + quad * 8]);
#pragma unroll
        for (int j = 0; j < 4; j++)
            bfr[j] = *reinterpret_cast<const s16x8*>(&Bs[buf][(wn + j * 16 + l16) * BK + quad * 8]);
#pragma unroll
        for (int i = 0; i < 4; i++)
#pragma unroll
            for (int j = 0; j < 4; j++)
                acc[i][j] = __builtin_amdgcn_mfma_f32_16x16x32_bf16(af[i], bfr[j], acc[i][j], 0, 0, 0);
    };

    stage(0, 0);
    for (int k0 = 0; k0 < 512; k0 += 2 * BK) {
        __syncthreads();
        stage(1, k0 + BK);
        compute(0);
        __syncthreads();
        if (k0 + 2 * BK < 512) stage(0, k0 + 2 * BK);
        compute(1);
    }

    if (which == 2) {
        u16* O = vv + (long)b * HC;
#pragma unroll
        for (int i = 0; i < 4; i++) {
            const int mb = m0 + wm + i * 16 + quad * 4;
#pragma unroll
            for (int j = 0; j < 4; j++) {
                const int n = n0 + wn + j * 16 + l16;
#pragma unroll
                for (int r = 0; r < 4; r++)
                    O[(long)(mb + r) * 2048 + n] = f2bf(acc[i][j][r] + bv[mb + r]);
            }
        }
    } else {
        const float* bias = which ? bk : bq;
        u16* O = (which ? kT : qT) + (long)b * HC;
#pragma unroll
        for (int i = 0; i < 4; i++) {
            const int mb = m0 + wm + i * 16 + quad * 4;
#pragma unroll
            for (int j = 0; j < 4; j++) {
                const int n = n0 + wn + j * 16 + l16;
                ushort4 pk;
                pk.x = f2bf(acc[i][j][0] + bias[mb + 0]);
                pk.y = f2bf(acc[i][j][1] + bias[mb + 1]);
                pk.z = f2bf(acc[i][j][2] + bias[mb + 2]);
                pk.w = f2bf(acc[i][j][3] + bias[mb + 3]);
                *reinterpret_cast<ushort4*>(&O[(long)n * 512 + mb]) = pk;
            }
        }
    }
}

// ===================== legacy padded GEMM (fallback tiers, fp32-capable) =====================
template <int F32>
__device__ __forceinline__ void stage_tile(const char* G, int ld, int r0, int k0,
                                           u16* __restrict__ lds, int tid) {
    if (F32) {
        const float* g = (const float*)G;
#pragma unroll
        for (int s = 0; s < 4; s++) {
            const int c = tid + s * 256;
            const int row = c >> 3, col = (c & 7) * 4;
            const float4 v = *reinterpret_cast<const float4*>(g + (long)(r0 + row) * ld + k0 + col);
            ushort4 pk;
            pk.x = f2bf(v.x); pk.y = f2bf(v.y); pk.z = f2bf(v.z); pk.w = f2bf(v.w);
            *reinterpret_cast<ushort4*>(&lds[row * KPAD + col]) = pk;
        }
    } else {
        const u16* g = (const u16*)G;
#pragma unroll
        for (int s = 0; s < 2; s++) {
            const int c = tid + s * 256;
            const int row = c >> 2, col = (c & 3) * 8;
            const uint4 v = *reinterpret_cast<const uint4*>(g + (long)(r0 + row) * ld + k0 + col);
            *reinterpret_cast<uint4*>(&lds[row * KPAD + col]) = v;
        }
    }
}

template <int EPI, int AF32, int BF32>
__global__ __launch_bounds__(256) void gemm_tn(const void* __restrict__ Agv, long sA,
                                               const void* __restrict__ Bgv, long sB,
                                               const float* __restrict__ bias,
                                               const float* __restrict__ Xg, long sX,
                                               void* __restrict__ Ogv, long sO,
                                               int K, int lda, int ldb, int ldo,
                                               float scale) {
    const int b = blockIdx.z;
    const char* A8 = (const char*)Agv + (long)b * sA * (AF32 ? 4 : 2);
    const char* B8 = (const char*)Bgv + (long)b * sB * (BF32 ? 4 : 2);
    const int m0 = blockIdx.y * BM;
    const int n0 = blockIdx.x * BN;

    __shared__ __align__(16) u16 As[BM * KPAD];
    __shared__ __align__(16) u16 Bs[BN * KPAD];

    const int tid = threadIdx.x;
    const int wave = tid >> 6;
    const int lane = tid & 63;
    const int quad = lane >> 4;
    const int l16 = lane & 15;
    const int wm = (wave >> 1) * 64;
    const int wn = (wave & 1) * 64;

    f32x4 acc[4][4];
#pragma unroll
    for (int i = 0; i < 4; i++)
#pragma unroll
        for (int j = 0; j < 4; j++) acc[i][j] = f32x4{0.f, 0.f, 0.f, 0.f};

    for (int k0 = 0; k0 < K; k0 += BK) {
        __syncthreads();
        stage_tile<AF32>(A8, lda, m0, k0, As, tid);
        stage_tile<BF32>(B8, ldb, n0, k0, Bs, tid);
        __syncthreads();
        s16x8 af[4], bfr[4];
#pragma unroll
        for (int i = 0; i < 4; i++)
            af[i] = *reinterpret_cast<const s16x8*>(&As[(wm + i * 16 + l16) * KPAD + quad * 8]);
#pragma unroll
        for (int j = 0; j < 4; j++)
            bfr[j] = *reinterpret_cast<const s16x8*>(&Bs[(wn + j * 16 + l16) * KPAD + quad * 8]);
#pragma unroll
        for (int i = 0; i < 4; i++)
#pragma unroll
            for (int j = 0; j < 4; j++)
                acc[i][j] = __builtin_amdgcn_mfma_f32_16x16x32_bf16(af[i], bfr[j], acc[i][j], 0, 0, 0);
    }

#pragma unroll
    for (int i = 0; i < 4; i++) {
        const int mb = m0 + wm + i * 16 + quad * 4;
#pragma unroll
        for (int j = 0; j < 4; j++) {
            const int n = n0 + wn + j * 16 + l16;
            if (EPI == 0) {
                u16* O = (u16*)Ogv + (long)b * sO;
#pragma unroll
                for (int r = 0; r < 4; r++) {
                    float vv = acc[i][j][r] * scale;
                    if (bias) vv += bias[mb + r];
                    O[(long)(mb + r) * ldo + n] = f2bf(vv);
                }
            } else if (EPI == 1) {
                u16* O = (u16*)Ogv + (long)b * sO;
                ushort4 pk;
                pk.x = f2bf(acc[i][j][0] + bias[mb + 0]);
                pk.y = f2bf(acc[i][j][1] + bias[mb + 1]);
                pk.z = f2bf(acc[i][j][2] + bias[mb + 2]);
                pk.w = f2bf(acc[i][j][3] + bias[mb + 3]);
                *reinterpret_cast<ushort4*>(&O[(long)n * ldo + mb]) = pk;
            } else {
                float* O = (float*)Ogv + (long)b * sO;
                const float* X = Xg + (long)b * sX;
                const float bn = bias[n];
                const float4 xv = *reinterpret_cast<const float4*>(&X[(long)n * ldo + mb]);
                float4 pk;
                pk.x = acc[i][j][0] + bn + xv.x;
                pk.y = acc[i][j][1] + bn + xv.y;
                pk.z = acc[i][j][2] + bn + xv.z;
                pk.w = acc[i][j][3] + bn + xv.w;
                *reinterpret_cast<float4*>(&O[(long)n * ldo + mb]) = pk;
            }
        }
    }
}

extern "C" void kernel_launch(void* const* d_in, const int* in_sizes, int n_in,
                              void* d_out, int out_size, void* d_ws, size_t ws_size,
                              hipStream_t stream) {
    const float* x     = (const float*)d_in[0];
    const float* gamma = (const float*)d_in[1];
    const float* beta  = (const float*)d_in[2];
    const float* wq    = (const float*)d_in[3];
    const float* bq    = (const float*)d_in[4];
    const float* wk    = (const float*)d_in[5];
    const float* bk    = (const float*)d_in[6];
    const float* wv    = (const float*)d_in[7];
    const float* bv    = (const float*)d_in[8];
    const float* wp    = (const float*)d_in[9];
    const float* bp    = (const float*)d_in[10];
    float* out = (float*)d_out;

    const long HC = (long)2048 * 512;
    const long HH = (long)2048 * 2048;
    const long WSZ = 512 * 512;
    const float scl = 0.044194173824159216f;   // 1/sqrt(512)

    char* ws = (char*)d_ws;
    float* meanb = (float*)ws;
    float* rstdb = (float*)(ws + 1024);
    u16* base = (u16*)(ws + 4096);

    const size_t FULL_NEED   = 4096 + 2 * (size_t)(24 * HC + 8 * HH);     // 117,444,608
    const size_t MED_NEED    = 4096 + 2 * (size_t)(32 * HC + HH);         //  75,501,568
    const size_t SMALL_NEED  = 4096 + 2 * (size_t)(4 * HC + HH);          //  16,781,312
    const size_t CHUNK512    = 4096 + 2 * (size_t)(4 * HC + 512 * 2048);  //  10,489,856

    gn_stats<<<256, 256, 0, stream>>>(x, meanb, rstdb);

    if (ws_size >= FULL_NEED) {
        // ---- FULL: all-batched, dbuf-async GEMMs, fused softmax+PV ----
        u16* qT  = base;                       // [B,H,C]
        u16* kT  = qT + 8 * HC;                // [B,H,C]; dead after S-GEMM -> stats scratch
        u16* vv  = kT + 8 * HC;                // [B,C,H]
        u16* Sb  = vv + 8 * HC;                // [B,H,H]
        u16* hnT = Sb;                         // overlay: dead before S written
        u16* wb3 = Sb + 8 * HH - 3 * WSZ;      // overlay: wq|wk|wv bf16, dead after QKV
        u16* hT  = qT;                         // overlay: qT dead after S-GEMM
        u16* wpb = vv;                         // overlay: vv dead after PV
        float* mrow = (float*)kT;              // 64 KB inside dead kT
        float* linv = mrow + 16384;

        w2bf<<<dim3(256, 3), 256, 0, stream>>>(wq, wk, wv, wb3);
        gn_apply_t<<<dim3(32, 8, 8), 256, 0, stream>>>(x, gamma, beta, meanb, rstdb, hnT);
        qkv_a<<<dim3(16, 4, 24), 256, 0, stream>>>(wb3, hnT, bq, bk, bv, qT, kT, vv);
        gemm_tn_a<0><<<dim3(16, 16, 8), 256, 0, stream>>>(qT, HC, kT, HC, nullptr, nullptr, 0,
                                                          Sb, HH, 512, 512, 512, 2048, scl);
        row_stats<<<4096, 256, 0, stream>>>(Sb, mrow, linv);
        pv_fused<<<dim3(4, 32, 8), 256, 0, stream>>>(Sb, vv, mrow, linv, hT);
        w2bf<<<dim3(256, 1), 256, 0, stream>>>(wp, wp, wp, wpb);
        gemm_tn_a<2><<<dim3(4, 16, 8), 256, 0, stream>>>(hT, HC, wpb, 0, bp, x, HC,
                                                         out, HC, 512, 512, 512, 2048, 1.f);
    } else if (ws_size >= MED_NEED) {
        u16* hnT = base;
        u16* qT  = hnT + 8 * HC;
        u16* kT  = qT + 8 * HC;
        u16* vv  = kT + 8 * HC;
        u16* Sb  = vv + 8 * HC;
        u16* hT  = hnT;
        gn_apply_t<<<dim3(32, 8, 8), 256, 0, stream>>>(x, gamma, beta, meanb, rstdb, hnT);
        gemm_tn<1, 1, 0><<<dim3(16, 4, 8), 256, 0, stream>>>(wq, 0, hnT, HC, bq, nullptr, 0,
                                                             qT, HC, 512, 512, 512, 512, 1.f);
        gemm_tn<1, 1, 0><<<dim3(16, 4, 8), 256, 0, stream>>>(wk, 0, hnT, HC, bk, nullptr, 0,
                                                             kT, HC, 512, 512, 512, 512, 1.f);
        gemm_tn<0, 1, 0><<<dim3(16, 4, 8), 256, 0, stream>>>(wv, 0, hnT, HC, bv, nullptr, 0,
                                                             vv, HC, 512, 512, 512, 2048, 1.f);
        for (int b = 0; b < 8; b++) {
            gemm_tn<0, 0, 0><<<dim3(16, 16, 1), 256, 0, stream>>>(qT + b * HC, 0, kT + b * HC, 0,
                                                                  nullptr, nullptr, 0, Sb, 0,
                                                                  512, 512, 512, 2048, scl);
            softmax_rows<<<2048, 256, 0, stream>>>(Sb);
            gemm_tn<0, 0, 0><<<dim3(4, 16, 1), 256, 0, stream>>>(Sb, 0, vv + b * HC, 0,
                                                                 nullptr, nullptr, 0, hT + b * HC, 0,
                                                                 2048, 2048, 2048, 512, 1.f);
        }
        gemm_tn<2, 0, 1><<<dim3(4, 16, 8), 256, 0, stream>>>(hT, HC, wp, 0, bp, x, HC,
                                                             out, HC, 512, 512, 512, 2048, 1.f);
    } else {
        const int CH = (ws_size >= SMALL_NEED) ? 2048 : ((ws_size >= CHUNK512) ? 512 : 128);
        u16* hn = base;
        u16* q  = hn + HC;
        u16* k  = q + HC;
        u16* v  = k + HC;
        u16* Sc = v + HC;
        u16* hT = hn;
        for (int b = 0; b < 8; b++) {
            const float* xb = x + (long)b * HC;
            gn_apply_t<<<dim3(32, 8, 1), 256, 0, stream>>>(xb, gamma, beta,
                                                           meanb + b * 32, rstdb + b * 32, hn);
            gemm_tn<1, 1, 0><<<dim3(16, 4, 1), 256, 0, stream>>>(wq, 0, hn, 0, bq, nullptr, 0,
                                                                 q, 0, 512, 512, 512, 512, 1.f);
            gemm_tn<1, 1, 0><<<dim3(16, 4, 1), 256, 0, stream>>>(wk, 0, hn, 0, bk, nullptr, 0,
                                                                 k, 0, 512, 512, 512, 512, 1.f);
            gemm_tn<0, 1, 0><<<dim3(16, 4, 1), 256, 0, stream>>>(wv, 0, hn, 0, bv, nullptr, 0,
                                                                 v, 0, 512, 512, 512, 2048, 1.f);
            for (int i0 = 0; i0 < 2048; i0 += CH) {
                gemm_tn<0, 0, 0><<<dim3(16, CH / 128, 1), 256, 0, stream>>>(
                    q + (long)i0 * 512, 0, k, 0, nullptr, nullptr, 0, Sc, 0,
                    512, 512, 512, 2048, scl);
                softmax_rows<<<CH, 256, 0, stream>>>(Sc);
                gemm_tn<0, 0, 0><<<dim3(4, CH / 128, 1), 256, 0, stream>>>(
                    Sc, 0, v, 0, nullptr, nullptr, 0, hT + (long)i0 * 512, 0,
                    2048, 2048, 2048, 512, 1.f);
            }
            gemm_tn<2, 0, 1><<<dim3(4, 16, 1), 256, 0, stream>>>(hT, 0, wp, 0, bp, xb, 0,
                                                                 out + (long)b * HC, 0,
                                                                 512, 512, 512, 2048, 1.f);
        }
    }
}

// Round 9
// 317.395 us; speedup vs baseline: 1.0960x; 1.0960x over previous
//
#include <hip/hip_runtime.h>
#include <stdint.h>

typedef unsigned short u16;
typedef short s16x8 __attribute__((ext_vector_type(8)));
typedef float f32x4 __attribute__((ext_vector_type(4)));

#define BM 128
#define BN 128
#define BK 32
#define KPAD 40   // padded LDS row stride for the legacy (non-async) kernel

__device__ __forceinline__ float bf2f(u16 b) {
    union { unsigned int u; float f; } v; v.u = ((unsigned int)b) << 16; return v.f;
}
__device__ __forceinline__ u16 f2bf(float f) {
    union { float f; unsigned int u; } v; v.f = f;
    unsigned int u = v.u;
    u += 0x7fffu + ((u >> 16) & 1u);   // RNE
    return (u16)(u >> 16);
}
__device__ __forceinline__ void async_cp16(const u16* g, u16* l) {
    // global -> LDS direct copy, 16 B per lane; LDS dest = wave-uniform base + lane*16
    __builtin_amdgcn_global_load_lds((const __attribute__((address_space(1))) void*)g,
                                     (__attribute__((address_space(3))) void*)l, 16, 0, 0);
}

// ---------------- GroupNorm statistics: one block per (b,g), fp32 input ----------------
__global__ __launch_bounds__(256) void gn_stats(const float* __restrict__ x,
                                                float* __restrict__ mean,
                                                float* __restrict__ rstd) {
    const int bg = blockIdx.x;
    const float* p = x + (long)bg * 16 * 2048;     // 32768 fp32 per group
    float s = 0.f, ss = 0.f;
    for (int it = 0; it < 32; it++) {
        const float4 v = *reinterpret_cast<const float4*>(p + ((it * 256 + threadIdx.x) << 2));
        s += v.x + v.y + v.z + v.w;
        ss += v.x * v.x + v.y * v.y + v.z * v.z + v.w * v.w;
    }
    const int lane = threadIdx.x & 63, wave = threadIdx.x >> 6;
#pragma unroll
    for (int o = 32; o > 0; o >>= 1) { s += __shfl_down(s, o, 64); ss += __shfl_down(ss, o, 64); }
    __shared__ float rb[8];
    if (lane == 0) { rb[wave] = s; rb[4 + wave] = ss; }
    __syncthreads();
    if (threadIdx.x == 0) {
        float S = rb[0] + rb[1] + rb[2] + rb[3];
        float SS = rb[4] + rb[5] + rb[6] + rb[7];
        float mu = S * (1.f / 32768.f);
        float var = SS * (1.f / 32768.f) - mu * mu;
        mean[bg] = mu;
        rstd[bg] = rsqrtf(var + 1e-6f);
    }
}

// ---------- GroupNorm apply + transpose: fp32 x -> bf16 hnT[h, c] ----------
__global__ __launch_bounds__(256) void gn_apply_t(const float* __restrict__ x,
                                                  const float* __restrict__ gamma,
                                                  const float* __restrict__ beta,
                                                  const float* __restrict__ mean,
                                                  const float* __restrict__ rstd,
                                                  u16* __restrict__ hnT) {
    const int b = blockIdx.z, c0 = blockIdx.y * 64, h0 = blockIdx.x * 64;
    __shared__ __align__(16) u16 T[64][72];
    const int tid = threadIdx.x;
#pragma unroll
    for (int sidx = 0; sidx < 4; sidx++) {
        int ch = tid + sidx * 256;                 // 1024 float4-chunks
        int cc = ch >> 4, h4 = (ch & 15) * 4;
        int c = c0 + cc;
        float mu = mean[b * 32 + (c >> 4)], rs = rstd[b * 32 + (c >> 4)];
        float ga = gamma[c], be = beta[c];
        const float4 v = *reinterpret_cast<const float4*>(x + ((long)b * 512 + c) * 2048 + h0 + h4);
        ushort4 pk;
        pk.x = f2bf((v.x - mu) * rs * ga + be);
        pk.y = f2bf((v.y - mu) * rs * ga + be);
        pk.z = f2bf((v.z - mu) * rs * ga + be);
        pk.w = f2bf((v.w - mu) * rs * ga + be);
        *reinterpret_cast<ushort4*>(&T[cc][h4]) = pk;
    }
    __syncthreads();
#pragma unroll
    for (int sidx = 0; sidx < 2; sidx++) {
        int ch = tid + sidx * 256;                 // 512 uint4-chunks
        int hh = ch >> 3, c8 = (ch & 7) * 8;
        unsigned int o[4];
#pragma unroll
        for (int i = 0; i < 4; i++) {
            u16 lo = T[c8 + 2 * i][hh];
            u16 hi = T[c8 + 2 * i + 1][hh];
            o[i] = (unsigned int)lo | ((unsigned int)hi << 16);
        }
        *reinterpret_cast<uint4*>(hnT + ((long)b * 2048 + h0 + hh) * 512 + c0 + c8) =
            uint4{o[0], o[1], o[2], o[3]};
    }
}

// ---------------- fp32 -> bf16 weight conversion (512x512 each, y selects src) ----------------
__global__ __launch_bounds__(256) void w2bf(const float* __restrict__ a,
                                            const float* __restrict__ b,
                                            const float* __restrict__ c,
                                            u16* __restrict__ dst) {
    const float* s = (blockIdx.y == 0) ? a : (blockIdx.y == 1) ? b : c;
    const int i = (blockIdx.x * 256 + threadIdx.x) * 4;
    const float4 v = *reinterpret_cast<const float4*>(s + i);
    ushort4 p;
    p.x = f2bf(v.x); p.y = f2bf(v.y); p.z = f2bf(v.z); p.w = f2bf(v.w);
    *reinterpret_cast<ushort4*>(dst + (long)blockIdx.y * 262144 + i) = p;
}

// ------------------ softmax over rows of S[i, :] (bf16) in place ------------------
__global__ __launch_bounds__(256) void softmax_rows(u16* __restrict__ S) {
    u16* p = S + (long)blockIdx.x * 2048;
    const int tid = threadIdx.x;
    uint4 v = *reinterpret_cast<const uint4*>(p + (tid << 3));
    unsigned int w[4] = {v.x, v.y, v.z, v.w};
    float f[8];
#pragma unroll
    for (int i = 0; i < 4; i++) {
        f[2 * i]     = bf2f((u16)(w[i] & 0xffffu));
        f[2 * i + 1] = bf2f((u16)(w[i] >> 16));
    }
    float m = f[0];
#pragma unroll
    for (int i = 1; i < 8; i++) m = fmaxf(m, f[i]);
    const int lane = tid & 63, wave = tid >> 6;
#pragma unroll
    for (int o = 32; o > 0; o >>= 1) m = fmaxf(m, __shfl_down(m, o, 64));
    __shared__ float rb[4];
    __shared__ float bc;
    if (lane == 0) rb[wave] = m;
    __syncthreads();
    if (tid == 0) bc = fmaxf(fmaxf(rb[0], rb[1]), fmaxf(rb[2], rb[3]));
    __syncthreads();
    m = bc;
    float s = 0.f;
#pragma unroll
    for (int i = 0; i < 8; i++) { f[i] = __expf(f[i] - m); s += f[i]; }
#pragma unroll
    for (int o = 32; o > 0; o >>= 1) s += __shfl_down(s, o, 64);
    __syncthreads();
    if (lane == 0) rb[wave] = s;
    __syncthreads();
    if (tid == 0) bc = 1.f / (rb[0] + rb[1] + rb[2] + rb[3]);
    __syncthreads();
    const float inv = bc;
#pragma unroll
    for (int i = 0; i < 4; i++)
        w[i] = (unsigned int)f2bf(f[2 * i] * inv) | ((unsigned int)f2bf(f[2 * i + 1] * inv) << 16);
    *reinterpret_cast<uint4*>(p + (tid << 3)) = uint4{w[0], w[1], w[2], w[3]};
}

// ===================== ASYNC double-buffered MFMA GEMM (bf16 operands) =====================
// SWIZ 0: normal 2D grid (x = n-tile, y = m-tile).
// SWIZ 1: 1D grid of 64 (4 n x 16 m); the 4 n-tiles sharing an A-strip get the same
//         bx%8 (same XCD) in consecutive slots -> A-strip fetched once per XCD.
// SWIZ 2: 1D grid of 256 (16 n x 16 m); each XCD owns a 4m x 8n quadrant.
template <int EPI, int SWIZ>
__global__ __launch_bounds__(256) void gemm_tn_a(const u16* __restrict__ Ag, long sA,
                                                 const u16* __restrict__ Bg, long sB,
                                                 const float* __restrict__ bias,
                                                 const float* __restrict__ Xg, long sX,
                                                 void* __restrict__ Ogv, long sO,
                                                 int K, int lda, int ldb, int ldo,
                                                 float scale) {
    const int b = blockIdx.z;
    Ag += (long)b * sA;
    Bg += (long)b * sB;
    int tx, ty;
    if (SWIZ == 1) {
        const int xcd = blockIdx.x & 7, s = blockIdx.x >> 3;
        ty = xcd + 8 * (s >> 2);
        tx = s & 3;
    } else if (SWIZ == 2) {
        const int xcd = blockIdx.x & 7, s = blockIdx.x >> 3;
        ty = (xcd & 3) * 4 + (s & 3);
        tx = (xcd >> 2) * 8 + (s >> 2);
    } else {
        tx = blockIdx.x; ty = blockIdx.y;
    }
    const int m0 = ty * BM;
    const int n0 = tx * BN;

    __shared__ __align__(16) u16 As[2][BM * BK];
    __shared__ __align__(16) u16 Bs[2][BN * BK];

    const int tid = threadIdx.x;
    const int wave = tid >> 6;
    const int lane = tid & 63;
    const int quad = lane >> 4;
    const int l16 = lane & 15;
    const int wm = (wave >> 1) * 64;
    const int wn = (wave & 1) * 64;
    const int rl = lane >> 2;
    const int cl = (lane & 3) * 8;

    f32x4 acc[4][4];
#pragma unroll
    for (int i = 0; i < 4; i++)
#pragma unroll
        for (int j = 0; j < 4; j++) acc[i][j] = f32x4{0.f, 0.f, 0.f, 0.f};

    auto stage = [&](int buf, int k0) {
#pragma unroll
        for (int j = 0; j < 2; j++) {
            const int rbase = wave * 32 + j * 16;
            async_cp16(Ag + (long)(m0 + rbase + rl) * lda + k0 + cl, &As[buf][rbase * BK]);
            async_cp16(Bg + (long)(n0 + rbase + rl) * ldb + k0 + cl, &Bs[buf][rbase * BK]);
        }
    };
    auto compute = [&](int buf) {
        s16x8 af[4], bfr[4];
#pragma unroll
        for (int i = 0; i < 4; i++)
            af[i] = *reinterpret_cast<const s16x8*>(&As[buf][(wm + i * 16 + l16) * BK + quad * 8]);
#pragma unroll
        for (int j = 0; j < 4; j++)
            bfr[j] = *reinterpret_cast<const s16x8*>(&Bs[buf][(wn + j * 16 + l16) * BK + quad * 8]);
#pragma unroll
        for (int i = 0; i < 4; i++)
#pragma unroll
            for (int j = 0; j < 4; j++)
                acc[i][j] = __builtin_amdgcn_mfma_f32_16x16x32_bf16(af[i], bfr[j], acc[i][j], 0, 0, 0);
    };

    stage(0, 0);
    for (int k0 = 0; k0 < K; k0 += 2 * BK) {
        __syncthreads();
        stage(1, k0 + BK);
        compute(0);
        __syncthreads();
        if (k0 + 2 * BK < K) stage(0, k0 + 2 * BK);
        compute(1);
    }

#pragma unroll
    for (int i = 0; i < 4; i++) {
        const int mb = m0 + wm + i * 16 + quad * 4;
#pragma unroll
        for (int j = 0; j < 4; j++) {
            const int n = n0 + wn + j * 16 + l16;
            if (EPI == 0) {
                u16* O = (u16*)Ogv + (long)b * sO;
#pragma unroll
                for (int r = 0; r < 4; r++) {
                    float vv = acc[i][j][r] * scale;
                    if (bias) vv += bias[mb + r];
                    O[(long)(mb + r) * ldo + n] = f2bf(vv);
                }
            } else if (EPI == 1) {
                u16* O = (u16*)Ogv + (long)b * sO;
                ushort4 pk;
                pk.x = f2bf(acc[i][j][0] + bias[mb + 0]);
                pk.y = f2bf(acc[i][j][1] + bias[mb + 1]);
                pk.z = f2bf(acc[i][j][2] + bias[mb + 2]);
                pk.w = f2bf(acc[i][j][3] + bias[mb + 3]);
                *reinterpret_cast<ushort4*>(&O[(long)n * ldo + mb]) = pk;
            } else {
                float* O = (float*)Ogv + (long)b * sO;
                const float* X = Xg + (long)b * sX;
                const float bn = bias[n];
                const float4 xv = *reinterpret_cast<const float4*>(&X[(long)n * ldo + mb]);
                float4 pk;
                pk.x = acc[i][j][0] + bn + xv.x;
                pk.y = acc[i][j][1] + bn + xv.y;
                pk.z = acc[i][j][2] + bn + xv.z;
                pk.w = acc[i][j][3] + bn + xv.w;
                *reinterpret_cast<float4*>(&O[(long)n * ldo + mb]) = pk;
            }
        }
    }
}

// ===================== merged QKV GEMM, XCD-swizzled: grid (192,1,8) =====================
// 12 blocks sharing an hnT strip (4 m-tiles x 3 outputs) co-locate on one XCD.
__global__ __launch_bounds__(256) void qkv_a(const u16* __restrict__ wb3,
                                             const u16* __restrict__ hnT,
                                             const float* __restrict__ bq,
                                             const float* __restrict__ bk,
                                             const float* __restrict__ bv,
                                             u16* __restrict__ qT, u16* __restrict__ kT,
                                             u16* __restrict__ vv) {
    const long HC = 1048576;
    const int b = blockIdx.z;
    const int xcd = blockIdx.x & 7, s = blockIdx.x >> 3;   // s in [0,24)
    const int hi = (s >= 12) ? 1 : 0;
    const int yy = s - hi * 12;                            // [0,12)
    const int x = xcd + 8 * hi;                            // n-tile [0,16)
    const int which = yy >> 2;                             // 0=q 1=k 2=v
    const int my = yy & 3;                                 // m-tile [0,4)
    const u16* Ag = wb3 + which * 262144;
    const u16* Bg = hnT + (long)b * HC;
    const int m0 = my * BM;
    const int n0 = x * BN;

    __shared__ __align__(16) u16 As[2][BM * BK];
    __shared__ __align__(16) u16 Bs[2][BN * BK];

    const int tid = threadIdx.x;
    const int wave = tid >> 6;
    const int lane = tid & 63;
    const int quad = lane >> 4;
    const int l16 = lane & 15;
    const int wm = (wave >> 1) * 64;
    const int wn = (wave & 1) * 64;
    const int rl = lane >> 2;
    const int cl = (lane & 3) * 8;

    f32x4 acc[4][4];
#pragma unroll
    for (int i = 0; i < 4; i++)
#pragma unroll
        for (int j = 0; j < 4; j++) acc[i][j] = f32x4{0.f, 0.f, 0.f, 0.f};

    auto stage = [&](int buf, int k0) {
#pragma unroll
        for (int j = 0; j < 2; j++) {
            const int rbase = wave * 32 + j * 16;
            async_cp16(Ag + (long)(m0 + rbase + rl) * 512 + k0 + cl, &As[buf][rbase * BK]);
            async_cp16(Bg + (long)(n0 + rbase + rl) * 512 + k0 + cl, &Bs[buf][rbase * BK]);
        }
    };
    auto compute = [&](int buf) {
        s16x8 af[4], bfr[4];
#pragma unroll
        for (int i = 0; i < 4; i++)
            af[i] = *reinterpret_cast<const s16x8*>(&As[buf][(wm + i * 16 + l16) * BK + quad * 8]);
#pragma unroll
        for (int j = 0; j < 4; j++)
            bfr[j] = *reinterpret_cast<const s16x8*>(&Bs[buf][(wn + j * 16 + l16) * BK + quad * 8]);
#pragma unroll
        for (int i = 0; i < 4; i++)
#pragma unroll
            for (int j = 0; j < 4; j++)
                acc[i][j] = __builtin_amdgcn_mfma_f32_16x16x32_bf16(af[i], bfr[j], acc[i][j], 0, 0, 0);
    };

    stage(0, 0);
    for (int k0 = 0; k0 < 512; k0 += 2 * BK) {
        __syncthreads();
        stage(1, k0 + BK);
        compute(0);
        __syncthreads();
        if (k0 + 2 * BK < 512) stage(0, k0 + 2 * BK);
        compute(1);
    }

    if (which == 2) {
        u16* O = vv + (long)b * HC;
#pragma unroll
        for (int i = 0; i < 4; i++) {
            const int mb = m0 + wm + i * 16 + quad * 4;
#pragma unroll
            for (int j = 0; j < 4; j++) {
                const int n = n0 + wn + j * 16 + l16;
#pragma unroll
                for (int r = 0; r < 4; r++)
                    O[(long)(mb + r) * 2048 + n] = f2bf(acc[i][j][r] + bv[mb + r]);
            }
        }
    } else {
        const float* bias = which ? bk : bq;
        u16* O = (which ? kT : qT) + (long)b * HC;
#pragma unroll
        for (int i = 0; i < 4; i++) {
            const int mb = m0 + wm + i * 16 + quad * 4;
#pragma unroll
            for (int j = 0; j < 4; j++) {
                const int n = n0 + wn + j * 16 + l16;
                ushort4 pk;
                pk.x = f2bf(acc[i][j][0] + bias[mb + 0]);
                pk.y = f2bf(acc[i][j][1] + bias[mb + 1]);
                pk.z = f2bf(acc[i][j][2] + bias[mb + 2]);
                pk.w = f2bf(acc[i][j][3] + bias[mb + 3]);
                *reinterpret_cast<ushort4*>(&O[(long)n * 512 + mb]) = pk;
            }
        }
    }
}

// ===================== legacy padded GEMM (fallback tiers, fp32-capable) =====================
template <int F32>
__device__ __forceinline__ void stage_tile(const char* G, int ld, int r0, int k0,
                                           u16* __restrict__ lds, int tid) {
    if (F32) {
        const float* g = (const float*)G;
#pragma unroll
        for (int s = 0; s < 4; s++) {
            const int c = tid + s * 256;
            const int row = c >> 3, col = (c & 7) * 4;
            const float4 v = *reinterpret_cast<const float4*>(g + (long)(r0 + row) * ld + k0 + col);
            ushort4 pk;
            pk.x = f2bf(v.x); pk.y = f2bf(v.y); pk.z = f2bf(v.z); pk.w = f2bf(v.w);
            *reinterpret_cast<ushort4*>(&lds[row * KPAD + col]) = pk;
        }
    } else {
        const u16* g = (const u16*)G;
#pragma unroll
        for (int s = 0; s < 2; s++) {
            const int c = tid + s * 256;
            const int row = c >> 2, col = (c & 3) * 8;
            const uint4 v = *reinterpret_cast<const uint4*>(g + (long)(r0 + row) * ld + k0 + col);
            *reinterpret_cast<uint4*>(&lds[row * KPAD + col]) = v;
        }
    }
}

template <int EPI, int AF32, int BF32>
__global__ __launch_bounds__(256) void gemm_tn(const void* __restrict__ Agv, long sA,
                                               const void* __restrict__ Bgv, long sB,
                                               const float* __restrict__ bias,
                                               const float* __restrict__ Xg, long sX,
                                               void* __restrict__ Ogv, long sO,
                                               int K, int lda, int ldb, int ldo,
                                               float scale) {
    const int b = blockIdx.z;
    const char* A8 = (const char*)Agv + (long)b * sA * (AF32 ? 4 : 2);
    const char* B8 = (const char*)Bgv + (long)b * sB * (BF32 ? 4 : 2);
    const int m0 = blockIdx.y * BM;
    const int n0 = blockIdx.x * BN;

    __shared__ __align__(16) u16 As[BM * KPAD];
    __shared__ __align__(16) u16 Bs[BN * KPAD];

    const int tid = threadIdx.x;
    const int wave = tid >> 6;
    const int lane = tid & 63;
    const int quad = lane >> 4;
    const int l16 = lane & 15;
    const int wm = (wave >> 1) * 64;
    const int wn = (wave & 1) * 64;

    f32x4 acc[4][4];
#pragma unroll
    for (int i = 0; i < 4; i++)
#pragma unroll
        for (int j = 0; j < 4; j++) acc[i][j] = f32x4{0.f, 0.f, 0.f, 0.f};

    for (int k0 = 0; k0 < K; k0 += BK) {
        __syncthreads();
        stage_tile<AF32>(A8, lda, m0, k0, As, tid);
        stage_tile<BF32>(B8, ldb, n0, k0, Bs, tid);
        __syncthreads();
        s16x8 af[4], bfr[4];
#pragma unroll
        for (int i = 0; i < 4; i++)
            af[i] = *reinterpret_cast<const s16x8*>(&As[(wm + i * 16 + l16) * KPAD + quad * 8]);
#pragma unroll
        for (int j = 0; j < 4; j++)
            bfr[j] = *reinterpret_cast<const s16x8*>(&Bs[(wn + j * 16 + l16) * KPAD + quad * 8]);
#pragma unroll
        for (int i = 0; i < 4; i++)
#pragma unroll
            for (int j = 0; j < 4; j++)
                acc[i][j] = __builtin_amdgcn_mfma_f32_16x16x32_bf16(af[i], bfr[j], acc[i][j], 0, 0, 0);
    }

#pragma unroll
    for (int i = 0; i < 4; i++) {
        const int mb = m0 + wm + i * 16 + quad * 4;
#pragma unroll
        for (int j = 0; j < 4; j++) {
            const int n = n0 + wn + j * 16 + l16;
            if (EPI == 0) {
                u16* O = (u16*)Ogv + (long)b * sO;
#pragma unroll
                for (int r = 0; r < 4; r++) {
                    float vv = acc[i][j][r] * scale;
                    if (bias) vv += bias[mb + r];
                    O[(long)(mb + r) * ldo + n] = f2bf(vv);
                }
            } else if (EPI == 1) {
                u16* O = (u16*)Ogv + (long)b * sO;
                ushort4 pk;
                pk.x = f2bf(acc[i][j][0] + bias[mb + 0]);
                pk.y = f2bf(acc[i][j][1] + bias[mb + 1]);
                pk.z = f2bf(acc[i][j][2] + bias[mb + 2]);
                pk.w = f2bf(acc[i][j][3] + bias[mb + 3]);
                *reinterpret_cast<ushort4*>(&O[(long)n * ldo + mb]) = pk;
            } else {
                float* O = (float*)Ogv + (long)b * sO;
                const float* X = Xg + (long)b * sX;
                const float bn = bias[n];
                const float4 xv = *reinterpret_cast<const float4*>(&X[(long)n * ldo + mb]);
                float4 pk;
                pk.x = acc[i][j][0] + bn + xv.x;
                pk.y = acc[i][j][1] + bn + xv.y;
                pk.z = acc[i][j][2] + bn + xv.z;
                pk.w = acc[i][j][3] + bn + xv.w;
                *reinterpret_cast<float4*>(&O[(long)n * ldo + mb]) = pk;
            }
        }
    }
}

extern "C" void kernel_launch(void* const* d_in, const int* in_sizes, int n_in,
                              void* d_out, int out_size, void* d_ws, size_t ws_size,
                              hipStream_t stream) {
    const float* x     = (const float*)d_in[0];
    const float* gamma = (const float*)d_in[1];
    const float* beta  = (const float*)d_in[2];
    const float* wq    = (const float*)d_in[3];
    const float* bq    = (const float*)d_in[4];
    const float* wk    = (const float*)d_in[5];
    const float* bk    = (const float*)d_in[6];
    const float* wv    = (const float*)d_in[7];
    const float* bv    = (const float*)d_in[8];
    const float* wp    = (const float*)d_in[9];
    const float* bp    = (const float*)d_in[10];
    float* out = (float*)d_out;

    const long HC = (long)2048 * 512;
    const long HH = (long)2048 * 2048;
    const long WSZ = 512 * 512;
    const float scl = 0.044194173824159216f;   // 1/sqrt(512)

    char* ws = (char*)d_ws;
    float* meanb = (float*)ws;
    float* rstdb = (float*)(ws + 1024);
    u16* base = (u16*)(ws + 4096);

    const size_t FULL_NEED   = 4096 + 2 * (size_t)(24 * HC + 8 * HH);     // 117,444,608
    const size_t MED_NEED    = 4096 + 2 * (size_t)(32 * HC + HH);         //  75,501,568
    const size_t SMALL_NEED  = 4096 + 2 * (size_t)(4 * HC + HH);          //  16,781,312
    const size_t CHUNK512    = 4096 + 2 * (size_t)(4 * HC + 512 * 2048);  //  10,489,856

    gn_stats<<<256, 256, 0, stream>>>(x, meanb, rstdb);

    if (ws_size >= FULL_NEED) {
        // ---- FULL: all-batched, dbuf-async GEMMs, XCD-swizzled grids ----
        u16* qT  = base;                       // [B,H,C]
        u16* kT  = qT + 8 * HC;                // [B,H,C]
        u16* vv  = kT + 8 * HC;                // [B,C,H]
        u16* Sb  = vv + 8 * HC;                // [B,H,H]
        u16* hnT = Sb;                         // overlay: dead before S written
        u16* wb3 = Sb + 8 * HH - 3 * WSZ;      // overlay: wq|wk|wv bf16, dead after QKV
        u16* hT  = qT;                         // overlay: qT dead after S-GEMM
        u16* wpb = vv;                         // overlay: vv dead after PV

        w2bf<<<dim3(256, 3), 256, 0, stream>>>(wq, wk, wv, wb3);
        gn_apply_t<<<dim3(32, 8, 8), 256, 0, stream>>>(x, gamma, beta, meanb, rstdb, hnT);
        qkv_a<<<dim3(192, 1, 8), 256, 0, stream>>>(wb3, hnT, bq, bk, bv, qT, kT, vv);
        gemm_tn_a<0, 2><<<dim3(256, 1, 8), 256, 0, stream>>>(qT, HC, kT, HC, nullptr, nullptr, 0,
                                                             Sb, HH, 512, 512, 512, 2048, scl);
        softmax_rows<<<16384, 256, 0, stream>>>(Sb);
        gemm_tn_a<0, 1><<<dim3(64, 1, 8), 256, 0, stream>>>(Sb, HH, vv, HC, nullptr, nullptr, 0,
                                                            hT, HC, 2048, 2048, 2048, 512, 1.f);
        w2bf<<<dim3(256, 1), 256, 0, stream>>>(wp, wp, wp, wpb);
        gemm_tn_a<2, 1><<<dim3(64, 1, 8), 256, 0, stream>>>(hT, HC, wpb, 0, bp, x, HC,
                                                            out, HC, 512, 512, 512, 2048, 1.f);
    } else if (ws_size >= MED_NEED) {
        u16* hnT = base;
        u16* qT  = hnT + 8 * HC;
        u16* kT  = qT + 8 * HC;
        u16* vv  = kT + 8 * HC;
        u16* Sb  = vv + 8 * HC;
        u16* hT  = hnT;
        gn_apply_t<<<dim3(32, 8, 8), 256, 0, stream>>>(x, gamma, beta, meanb, rstdb, hnT);
        gemm_tn<1, 1, 0><<<dim3(16, 4, 8), 256, 0, stream>>>(wq, 0, hnT, HC, bq, nullptr, 0,
                                                             qT, HC, 512, 512, 512, 512, 1.f);
        gemm_tn<1, 1, 0><<<dim3(16, 4, 8), 256, 0, stream>>>(wk, 0, hnT, HC, bk, nullptr, 0,
                                                             kT, HC, 512, 512, 512, 512, 1.f);
        gemm_tn<0, 1, 0><<<dim3(16, 4, 8), 256, 0, stream>>>(wv, 0, hnT, HC, bv, nullptr, 0,
                                                             vv, HC, 512, 512, 512, 2048, 1.f);
        for (int b = 0; b < 8; b++) {
            gemm_tn<0, 0, 0><<<dim3(16, 16, 1), 256, 0, stream>>>(qT + b * HC, 0, kT + b * HC, 0,
                                                                  nullptr, nullptr, 0, Sb, 0,
                                                                  512, 512, 512, 2048, scl);
            softmax_rows<<<2048, 256, 0, stream>>>(Sb);
            gemm_tn<0, 0, 0><<<dim3(4, 16, 1), 256, 0, stream>>>(Sb, 0, vv + b * HC, 0,
                                                                 nullptr, nullptr, 0, hT + b * HC, 0,
                                                                 2048, 2048, 2048, 512, 1.f);
        }
        gemm_tn<2, 0, 1><<<dim3(4, 16, 8), 256, 0, stream>>>(hT, HC, wp, 0, bp, x, HC,
                                                             out, HC, 512, 512, 512, 2048, 1.f);
    } else {
        const int CH = (ws_size >= SMALL_NEED) ? 2048 : ((ws_size >= CHUNK512) ? 512 : 128);
        u16* hn = base;
        u16* q  = hn + HC;
        u16* k  = q + HC;
        u16* v  = k + HC;
        u16* Sc = v + HC;
        u16* hT = hn;
        for (int b = 0; b < 8; b++) {
            const float* xb = x + (long)b * HC;
            gn_apply_t<<<dim3(32, 8, 1), 256, 0, stream>>>(xb, gamma, beta,
                                                           meanb + b * 32, rstdb + b * 32, hn);
            gemm_tn<1, 1, 0><<<dim3(16, 4, 1), 256, 0, stream>>>(wq, 0, hn, 0, bq, nullptr, 0,
                                                                 q, 0, 512, 512, 512, 512, 1.f);
            gemm_tn<1, 1, 0><<<dim3(16, 4, 1), 256, 0, stream>>>(wk, 0, hn, 0, bk, nullptr, 0,
                                                                 k, 0, 512, 512, 512, 512, 1.f);
            gemm_tn<0, 1, 0><<<dim3(16, 4, 1), 256, 0, stream>>>(wv, 0, hn, 0, bv, nullptr, 0,
                                                                 v, 0, 512, 512, 512, 2048, 1.f);
            for (int i0 = 0; i0 < 2048; i0 += CH) {
                gemm_tn<0, 0, 0><<<dim3(16, CH / 128, 1), 256, 0, stream>>>(
                    q + (long)i0 * 512, 0, k, 0, nullptr, nullptr, 0, Sc, 0,
                    512, 512, 512, 2048, scl);
                softmax_rows<<<CH, 256, 0, stream>>>(Sc);
                gemm_tn<0, 0, 0><<<dim3(4, CH / 128, 1), 256, 0, stream>>>(
                    Sc, 0, v, 0, nullptr, nullptr, 0, hT + (long)i0 * 512, 0,
                    2048, 2048, 2048, 512, 1.f);
            }
            gemm_tn<2, 0, 1><<<dim3(4, 16, 1), 256, 0, stream>>>(hT, 0, wp, 0, bp, xb, 0,
                                                                 out + (long)b * HC, 0,
                                                                 512, 512, 512, 2048, 1.f);
        }
    }
}